// Round 1
// baseline (27042.365 us; speedup 1.0000x reference)
//
#include <hip/hip_runtime.h>
#include <cstdint>

typedef _Float16 half8 __attribute__((ext_vector_type(8)));
typedef _Float16 half4v __attribute__((ext_vector_type(4)));
typedef float floatx4 __attribute__((ext_vector_type(4)));

__device__ __forceinline__ float sig_(float x) { return 1.f / (1.f + __expf(-x)); }
__device__ __forceinline__ float tanh_(float x) {
  x = fminf(15.f, fmaxf(-15.f, x));
  float e = __expf(2.f * x);
  return (e - 1.f) / (e + 1.f);
}

// ---------------- prep kernels ----------------
__global__ void cvt_x_kernel(const float* __restrict__ x, _Float16* __restrict__ xh, int n) {
  int i = (blockIdx.x * 256 + threadIdx.x) * 4;
  if (i < n) {
    const float4 v = *(const float4*)(x + i);
    half4v o = {(_Float16)v.x, (_Float16)v.y, (_Float16)v.z, (_Float16)v.w};
    *(half4v*)(xh + i) = o;
  }
}

// Permuted weight layout: row n (0..4095) of W*perm = w_{g}[u][:], u=n>>2, g=n&3.
// So block p of the recurrent kernel owns contiguous perm-cols [16p,16p+16).
__global__ void build_w_kernel(const float* w0, const float* w1, const float* w2, const float* w3,
                               const float* w4, const float* w5, const float* w6, const float* w7,
                               const float* b0, const float* b1, const float* b2, const float* b3,
                               _Float16* __restrict__ Wip, _Float16* __restrict__ Whp,
                               float* __restrict__ biasp) {
  int n = blockIdx.x;
  if (n < 8192) {
    const float* srcs[8] = {w0, w1, w2, w3, w4, w5, w6, w7};
    int which = n >> 12;  // 0 -> Wi, 1 -> Wh
    int row = n & 4095;
    int u = row >> 2, g = row & 3;
    const float* s = srcs[which * 4 + g] + (size_t)u * 1024;
    _Float16* dst = (which ? Whp : Wip) + (size_t)row * 1024;
    int t = threadIdx.x * 4;
    float4 v = *(const float4*)(s + t);
    half4v o = {(_Float16)v.x, (_Float16)v.y, (_Float16)v.z, (_Float16)v.w};
    *(half4v*)(dst + t) = o;
  } else {
    const float* bs[4] = {b0, b1, b2, b3};
    for (int idx = threadIdx.x; idx < 4096; idx += 256)
      biasp[idx] = bs[idx & 3][idx >> 2];
  }
}

__global__ void init_h_kernel(const float* __restrict__ hx, _Float16* __restrict__ hbuf,
                              unsigned int* __restrict__ cnt) {
  int i = blockIdx.x * 256 + threadIdx.x;
  if (i < 65536) hbuf[i] = (_Float16)hx[i];
  if (i == 0) *cnt = 0u;
}

// ---------------- precompute GEMM: G[t*64+b][ncol] = X @ Wi_perm^T + bias ----------------
// M=32768, N=4096, K=1024. m97-style: 128x128 tile, BK=32, global_load_lds w=16.
// LDS layout [kchunk][row][8] so the lane-contiguous DMA order matches frag reads.
__global__ __launch_bounds__(256) void gemm_g_kernel(const _Float16* __restrict__ Xh,
                                                     const _Float16* __restrict__ Wp,
                                                     const float* __restrict__ biasp,
                                                     _Float16* __restrict__ G) {
  __shared__ _Float16 Al[4][128][8];
  __shared__ _Float16 Bl[4][128][8];
  const int tid = threadIdx.x;
  const int w = tid >> 6, l = tid & 63;
  const int wm = (w >> 1) * 64, wn = (w & 1) * 64;
  const int ml = l & 15, kg = l >> 4;
  const int bm = blockIdx.x, bn = blockIdx.y;
  const int r0 = tid & 127, kc0 = tid >> 7;  // chunk c=tid -> kc 0..1; c=tid+256 -> kc 2..3
  const int kc1 = kc0 + 2;
  const size_t arow0 = (size_t)(bm * 128 + r0) * 1024;
  const size_t brow0 = (size_t)(bn * 128 + r0) * 1024;
  floatx4 acc[4][4] = {};
  for (int kt = 0; kt < 1024; kt += 32) {
    __syncthreads();
    __builtin_amdgcn_global_load_lds(
        (const __attribute__((address_space(1))) unsigned int*)(Xh + arow0 + kt + kc0 * 8),
        (__attribute__((address_space(3))) unsigned int*)&Al[kc0][r0][0], 16, 0, 0);
    __builtin_amdgcn_global_load_lds(
        (const __attribute__((address_space(1))) unsigned int*)(Xh + arow0 + kt + kc1 * 8),
        (__attribute__((address_space(3))) unsigned int*)&Al[kc1][r0][0], 16, 0, 0);
    __builtin_amdgcn_global_load_lds(
        (const __attribute__((address_space(1))) unsigned int*)(Wp + brow0 + kt + kc0 * 8),
        (__attribute__((address_space(3))) unsigned int*)&Bl[kc0][r0][0], 16, 0, 0);
    __builtin_amdgcn_global_load_lds(
        (const __attribute__((address_space(1))) unsigned int*)(Wp + brow0 + kt + kc1 * 8),
        (__attribute__((address_space(3))) unsigned int*)&Bl[kc1][r0][0], 16, 0, 0);
    __syncthreads();
    half8 af[4], bf[4];
#pragma unroll
    for (int i = 0; i < 4; ++i) af[i] = *(const half8*)&Al[kg][wm + i * 16 + ml][0];
#pragma unroll
    for (int j = 0; j < 4; ++j) bf[j] = *(const half8*)&Bl[kg][wn + j * 16 + ml][0];
#pragma unroll
    for (int i = 0; i < 4; ++i)
#pragma unroll
      for (int j = 0; j < 4; ++j)
        acc[i][j] = __builtin_amdgcn_mfma_f32_16x16x32_f16(af[i], bf[j], acc[i][j], 0, 0, 0);
  }
#pragma unroll
  for (int j = 0; j < 4; ++j) {
    const int col = bn * 128 + wn + j * 16 + ml;
    const float bj = biasp[col];
#pragma unroll
    for (int i = 0; i < 4; ++i)
#pragma unroll
      for (int r = 0; r < 4; ++r) {
        const size_t grow = (size_t)(bm * 128 + wm + i * 16 + kg * 4 + r);
        G[grow * 4096 + col] = (_Float16)(acc[i][j][r] + bj);
      }
  }
}

// ---------------- persistent recurrent kernel ----------------
// grid = 256 blocks (1/CU, all co-resident), 256 threads (4 waves).
// Block p owns hidden units [4p,4p+4) == perm gate cols [16p,16p+16).
// Wh slice lives in LDS for the whole kernel. h double-buffered fp16 in ws.
__global__ __launch_bounds__(256, 1) void lstm_rec_kernel(
    const _Float16* __restrict__ G, const _Float16* __restrict__ Whp,
    _Float16* __restrict__ hbuf, const float* __restrict__ cx,
    float* __restrict__ out, unsigned int* cnt) {
  const int p = blockIdx.x;
  const int tid = threadIdx.x;
  const int w = tid >> 6, l = tid & 63;
  const int ml = l & 15, kg = l >> 4;
  __shared__ _Float16 whl[16][1032];  // +8 pad: breaks 2KB-stride bank conflicts
  __shared__ float gl[64][20];        // gates [b][16], stride 20 for conflicts + f4 align

  for (int idx = tid; idx < 2048; idx += 256) {
    int row = idx >> 7, kc = idx & 127;
    *(half8*)&whl[row][kc * 8] = *(const half8*)&Whp[(size_t)(16 * p + row) * 1024 + kc * 8];
  }
  const int b = tid >> 2, u = tid & 3, U = 4 * p + u;
  float c = cx[b * 1024 + U];
  __syncthreads();

  unsigned int target = 0;
  for (int t = 0; t < 512; ++t) {
    const _Float16* hcur = hbuf + (size_t)(t & 1) * 65536;
    _Float16* hnxt = hbuf + (size_t)((t & 1) ^ 1) * 65536;

    // prefetch this step's input-projection slice (static data, used in epilogue)
    float gin[4];
#pragma unroll
    for (int r = 0; r < 4; ++r)
      gin[r] = (float)G[(size_t)(t * 64 + 16 * w + kg * 4 + r) * 4096 + p * 16 + ml];

    floatx4 acc0 = {0.f, 0.f, 0.f, 0.f}, acc1 = acc0, acc2 = acc0, acc3 = acc0;
    const _Float16* ap = hcur + (size_t)(16 * w + ml) * 1024 + kg * 8;
#pragma unroll
    for (int kk = 0; kk < 32; kk += 4) {
      half8 a0 = *(const half8*)(ap + kk * 32);
      half8 a1 = *(const half8*)(ap + kk * 32 + 32);
      half8 a2 = *(const half8*)(ap + kk * 32 + 64);
      half8 a3 = *(const half8*)(ap + kk * 32 + 96);
      half8 b0 = *(const half8*)&whl[ml][kk * 32 + kg * 8];
      half8 b1 = *(const half8*)&whl[ml][kk * 32 + 32 + kg * 8];
      half8 b2 = *(const half8*)&whl[ml][kk * 32 + 64 + kg * 8];
      half8 b3 = *(const half8*)&whl[ml][kk * 32 + 96 + kg * 8];
      acc0 = __builtin_amdgcn_mfma_f32_16x16x32_f16(a0, b0, acc0, 0, 0, 0);
      acc1 = __builtin_amdgcn_mfma_f32_16x16x32_f16(a1, b1, acc1, 0, 0, 0);
      acc2 = __builtin_amdgcn_mfma_f32_16x16x32_f16(a2, b2, acc2, 0, 0, 0);
      acc3 = __builtin_amdgcn_mfma_f32_16x16x32_f16(a3, b3, acc3, 0, 0, 0);
    }
    floatx4 a4 = (acc0 + acc1) + (acc2 + acc3);
#pragma unroll
    for (int r = 0; r < 4; ++r)
      gl[16 * w + kg * 4 + r][ml] = a4[r] + gin[r];
    __syncthreads();

    const float4 g4 = *(const float4*)&gl[b][u * 4];
    const float ig = sig_(g4.x), fg = sig_(g4.y);
    const float ag = tanh_(g4.z), og = sig_(g4.w);
    c = fg * c + ig * ag;
    const float h = og * tanh_(c);
    out[(size_t)t * 65536 + b * 1024 + U] = h;
    hnxt[b * 1024 + U] = (_Float16)h;
    if (t == 511) {
      out[(size_t)33554432 + b * 1024 + U] = h;   // hy
      out[(size_t)33619968 + b * 1024 + U] = c;   // cy
    }

    // grid barrier: release(all threads) -> arrive -> spin -> acquire(all threads)
    __threadfence();   // wbl2: h slice visible device-wide (cross-XCD via L3)
    __syncthreads();   // all threads of this block have released
    target += 256;
    if (tid == 0) {
      __hip_atomic_fetch_add(cnt, 1u, __ATOMIC_RELAXED, __HIP_MEMORY_SCOPE_AGENT);
      while (__hip_atomic_load(cnt, __ATOMIC_RELAXED, __HIP_MEMORY_SCOPE_AGENT) < target)
        __builtin_amdgcn_s_sleep(2);
    }
    __syncthreads();
    __threadfence();   // inv: next step's h loads refetch past stale L2
  }
}

// ---------------- launch ----------------
extern "C" void kernel_launch(void* const* d_in, const int* in_sizes, int n_in,
                              void* d_out, int out_size, void* d_ws, size_t ws_size,
                              hipStream_t stream) {
  const float* x    = (const float*)d_in[0];
  const float* hx   = (const float*)d_in[1];
  const float* cxp  = (const float*)d_in[2];
  const float* w_ii = (const float*)d_in[3];
  const float* w_fi = (const float*)d_in[4];
  const float* w_ai = (const float*)d_in[5];
  const float* w_oi = (const float*)d_in[6];
  const float* w_ih = (const float*)d_in[7];
  const float* w_fh = (const float*)d_in[8];
  const float* w_ah = (const float*)d_in[9];
  const float* w_oh = (const float*)d_in[10];
  const float* b_i  = (const float*)d_in[11];
  const float* b_f  = (const float*)d_in[12];
  const float* b_a  = (const float*)d_in[13];
  const float* b_o  = (const float*)d_in[14];
  float* out = (float*)d_out;

  char* ws = (char*)d_ws;
  _Float16* Xh      = (_Float16*)(ws);                 // 64 MB
  _Float16* Wip     = (_Float16*)(ws + 67108864);      // 8 MB
  _Float16* Whp     = (_Float16*)(ws + 75497472);      // 8 MB
  float* biasp      = (float*)(ws + 83886080);         // 16 KB
  _Float16* hbuf    = (_Float16*)(ws + 83902464);      // 256 KB (2 buffers)
  unsigned int* cnt = (unsigned int*)(ws + 84164608);  // barrier counter
  _Float16* G       = (_Float16*)(ws + 84164864);      // 256 MB
  if (ws_size < (size_t)84164864 + 268435456) return;  // insufficient workspace

  cvt_x_kernel<<<32768, 256, 0, stream>>>(x, Xh, 33554432);
  build_w_kernel<<<8193, 256, 0, stream>>>(w_ii, w_fi, w_ai, w_oi, w_ih, w_fh, w_ah, w_oh,
                                           b_i, b_f, b_a, b_o, Wip, Whp, biasp);
  init_h_kernel<<<256, 256, 0, stream>>>(hx, hbuf, cnt);
  gemm_g_kernel<<<dim3(256, 32), 256, 0, stream>>>(Xh, Wip, biasp, G);
  lstm_rec_kernel<<<256, 256, 0, stream>>>(G, Whp, hbuf, cxp, out, cnt);
}

// Round 2
// 6171.114 us; speedup vs baseline: 4.3821x; 4.3821x over previous
//
#include <hip/hip_runtime.h>
#include <cstdint>

typedef _Float16 half8 __attribute__((ext_vector_type(8)));
typedef _Float16 half4v __attribute__((ext_vector_type(4)));
typedef float floatx4 __attribute__((ext_vector_type(4)));
typedef unsigned long long u64;

__device__ __forceinline__ float sig_(float x) { return 1.f / (1.f + __expf(-x)); }
__device__ __forceinline__ float tanh_(float x) {
  x = fminf(15.f, fmaxf(-15.f, x));
  float e = __expf(2.f * x);
  return (e - 1.f) / (e + 1.f);
}

// ---------------- prep kernels ----------------
__global__ void cvt_x_kernel(const float* __restrict__ x, _Float16* __restrict__ xh, int n) {
  int i = (blockIdx.x * 256 + threadIdx.x) * 4;
  if (i < n) {
    const float4 v = *(const float4*)(x + i);
    half4v o = {(_Float16)v.x, (_Float16)v.y, (_Float16)v.z, (_Float16)v.w};
    *(half4v*)(xh + i) = o;
  }
}

// Permuted weight layout: row n (0..4095) of W*perm = w_{g}[u][:], u=n>>2, g=n&3.
// So block p of the recurrent kernel owns contiguous perm-cols [16p,16p+16).
__global__ void build_w_kernel(const float* w0, const float* w1, const float* w2, const float* w3,
                               const float* w4, const float* w5, const float* w6, const float* w7,
                               const float* b0, const float* b1, const float* b2, const float* b3,
                               _Float16* __restrict__ Wip, _Float16* __restrict__ Whp,
                               float* __restrict__ biasp) {
  int n = blockIdx.x;
  if (n < 8192) {
    const float* srcs[8] = {w0, w1, w2, w3, w4, w5, w6, w7};
    int which = n >> 12;  // 0 -> Wi, 1 -> Wh
    int row = n & 4095;
    int u = row >> 2, g = row & 3;
    const float* s = srcs[which * 4 + g] + (size_t)u * 1024;
    _Float16* dst = (which ? Whp : Wip) + (size_t)row * 1024;
    int t = threadIdx.x * 4;
    float4 v = *(const float4*)(s + t);
    half4v o = {(_Float16)v.x, (_Float16)v.y, (_Float16)v.z, (_Float16)v.w};
    *(half4v*)(dst + t) = o;
  } else {
    const float* bs[4] = {b0, b1, b2, b3};
    for (int idx = threadIdx.x; idx < 4096; idx += 256)
      biasp[idx] = bs[idx & 3][idx >> 2];
  }
}

// h buffers hold fp16 PAIRS packed in u32 (so h exchange can use dword/qword atomics)
__global__ void init_h_kernel(const float* __restrict__ hx, unsigned int* __restrict__ hbuf) {
  int i = blockIdx.x * 256 + threadIdx.x;
  if (i < 32768) {
    unsigned short lo = __builtin_bit_cast(unsigned short, (_Float16)hx[2 * i]);
    unsigned short hi = __builtin_bit_cast(unsigned short, (_Float16)hx[2 * i + 1]);
    hbuf[i] = (unsigned int)lo | ((unsigned int)hi << 16);
  }
}

__global__ void zero_flags_kernel(unsigned int* __restrict__ flags) {
  int i = blockIdx.x * 256 + threadIdx.x;
  if (i < 8192) flags[i] = 0u;
}

// ---------------- precompute GEMM: G[t*64+b][ncol] = X @ Wi_perm^T + bias ----------------
__global__ __launch_bounds__(256) void gemm_g_kernel(const _Float16* __restrict__ Xh,
                                                     const _Float16* __restrict__ Wp,
                                                     const float* __restrict__ biasp,
                                                     _Float16* __restrict__ G) {
  __shared__ _Float16 Al[4][128][8];
  __shared__ _Float16 Bl[4][128][8];
  const int tid = threadIdx.x;
  const int w = tid >> 6, l = tid & 63;
  const int wm = (w >> 1) * 64, wn = (w & 1) * 64;
  const int ml = l & 15, kg = l >> 4;
  const int bm = blockIdx.x, bn = blockIdx.y;
  const int r0 = tid & 127, kc0 = tid >> 7;
  const int kc1 = kc0 + 2;
  const size_t arow0 = (size_t)(bm * 128 + r0) * 1024;
  const size_t brow0 = (size_t)(bn * 128 + r0) * 1024;
  floatx4 acc[4][4] = {};
  for (int kt = 0; kt < 1024; kt += 32) {
    __syncthreads();
    __builtin_amdgcn_global_load_lds(
        (const __attribute__((address_space(1))) unsigned int*)(Xh + arow0 + kt + kc0 * 8),
        (__attribute__((address_space(3))) unsigned int*)&Al[kc0][r0][0], 16, 0, 0);
    __builtin_amdgcn_global_load_lds(
        (const __attribute__((address_space(1))) unsigned int*)(Xh + arow0 + kt + kc1 * 8),
        (__attribute__((address_space(3))) unsigned int*)&Al[kc1][r0][0], 16, 0, 0);
    __builtin_amdgcn_global_load_lds(
        (const __attribute__((address_space(1))) unsigned int*)(Wp + brow0 + kt + kc0 * 8),
        (__attribute__((address_space(3))) unsigned int*)&Bl[kc0][r0][0], 16, 0, 0);
    __builtin_amdgcn_global_load_lds(
        (const __attribute__((address_space(1))) unsigned int*)(Wp + brow0 + kt + kc1 * 8),
        (__attribute__((address_space(3))) unsigned int*)&Bl[kc1][r0][0], 16, 0, 0);
    __syncthreads();
    half8 af[4], bf[4];
#pragma unroll
    for (int i = 0; i < 4; ++i) af[i] = *(const half8*)&Al[kg][wm + i * 16 + ml][0];
#pragma unroll
    for (int j = 0; j < 4; ++j) bf[j] = *(const half8*)&Bl[kg][wn + j * 16 + ml][0];
#pragma unroll
    for (int i = 0; i < 4; ++i)
#pragma unroll
      for (int j = 0; j < 4; ++j)
        acc[i][j] = __builtin_amdgcn_mfma_f32_16x16x32_f16(af[i], bf[j], acc[i][j], 0, 0, 0);
  }
#pragma unroll
  for (int j = 0; j < 4; ++j) {
    const int col = bn * 128 + wn + j * 16 + ml;
    const float bj = biasp[col];
#pragma unroll
    for (int i = 0; i < 4; ++i)
#pragma unroll
      for (int r = 0; r < 4; ++r) {
        const size_t grow = (size_t)(bm * 128 + wm + i * 16 + kg * 4 + r);
        G[grow * 4096 + col] = (_Float16)(acc[i][j][r] + bj);
      }
  }
}

// ---------------- persistent recurrent kernel ----------------
// grid = 256 blocks (1/CU, all co-resident), 256 threads (4 waves).
// Block p owns hidden units [4p,4p+4) == perm gate cols [16p,16p+16).
// h exchange: relaxed AGENT-scope atomics (write-through / coherence-point reads;
// no L2 flush/inv needed). Barrier: per-block flag lines + all-thread poll.
__device__ __forceinline__ half8 lda_(const u64* hq, size_t idx) {
  union { u64 q[2]; half8 h; } u;
  u.q[0] = __hip_atomic_load(&hq[idx], __ATOMIC_RELAXED, __HIP_MEMORY_SCOPE_AGENT);
  u.q[1] = __hip_atomic_load(&hq[idx + 1], __ATOMIC_RELAXED, __HIP_MEMORY_SCOPE_AGENT);
  return u.h;
}

__global__ __launch_bounds__(256, 1) void lstm_rec_kernel(
    const _Float16* __restrict__ G, const _Float16* __restrict__ Whp,
    unsigned int* __restrict__ hbuf, const float* __restrict__ cx,
    float* __restrict__ out, unsigned int* __restrict__ flags) {
  const int p = blockIdx.x;
  const int tid = threadIdx.x;
  const int w = tid >> 6, l = tid & 63;
  const int ml = l & 15, kg = l >> 4;
  __shared__ _Float16 whl[16][1032];  // +8 pad: breaks 2KB-stride bank conflicts
  __shared__ float gl[64][20];        // gates [b][16]

  for (int idx = tid; idx < 2048; idx += 256) {
    int row = idx >> 7, kc = idx & 127;
    *(half8*)&whl[row][kc * 8] = *(const half8*)&Whp[(size_t)(16 * p + row) * 1024 + kc * 8];
  }
  const int b = tid >> 2, u = tid & 3, U = 4 * p + u;
  float c = cx[b * 1024 + U];
  __syncthreads();

  for (int t = 0; t < 512; ++t) {
    const u64* hq = (const u64*)(hbuf + (size_t)(t & 1) * 32768);
    unsigned int* hnxt = hbuf + (size_t)((t & 1) ^ 1) * 32768;

    // this step's input-projection slice (static, cached)
    float gin[4];
#pragma unroll
    for (int r = 0; r < 4; ++r)
      gin[r] = (float)G[(size_t)(t * 64 + 16 * w + kg * 4 + r) * 4096 + p * 16 + ml];

    floatx4 acc0 = {0.f, 0.f, 0.f, 0.f}, acc1 = acc0, acc2 = acc0, acc3 = acc0;
    const size_t abase = (size_t)(16 * w + ml) * 256 + kg * 2;  // u64 units
#pragma unroll
    for (int kk = 0; kk < 32; kk += 4) {
      half8 a0 = lda_(hq, abase + (kk + 0) * 8);
      half8 a1 = lda_(hq, abase + (kk + 1) * 8);
      half8 a2 = lda_(hq, abase + (kk + 2) * 8);
      half8 a3 = lda_(hq, abase + (kk + 3) * 8);
      half8 b0 = *(const half8*)&whl[ml][kk * 32 + kg * 8];
      half8 b1 = *(const half8*)&whl[ml][kk * 32 + 32 + kg * 8];
      half8 b2 = *(const half8*)&whl[ml][kk * 32 + 64 + kg * 8];
      half8 b3 = *(const half8*)&whl[ml][kk * 32 + 96 + kg * 8];
      acc0 = __builtin_amdgcn_mfma_f32_16x16x32_f16(a0, b0, acc0, 0, 0, 0);
      acc1 = __builtin_amdgcn_mfma_f32_16x16x32_f16(a1, b1, acc1, 0, 0, 0);
      acc2 = __builtin_amdgcn_mfma_f32_16x16x32_f16(a2, b2, acc2, 0, 0, 0);
      acc3 = __builtin_amdgcn_mfma_f32_16x16x32_f16(a3, b3, acc3, 0, 0, 0);
    }
    floatx4 a4 = (acc0 + acc1) + (acc2 + acc3);
#pragma unroll
    for (int r = 0; r < 4; ++r)
      gl[16 * w + kg * 4 + r][ml] = a4[r] + gin[r];
    __syncthreads();

    const float4 g4 = *(const float4*)&gl[b][u * 4];
    const float ig = sig_(g4.x), fg = sig_(g4.y);
    const float ag = tanh_(g4.z), og = sig_(g4.w);
    c = fg * c + ig * ag;
    const float h = og * tanh_(c);
    out[(size_t)t * 65536 + b * 1024 + U] = h;

    // publish h: packed fp16 pair, write-through agent store
    unsigned int mine = (unsigned int)__builtin_bit_cast(unsigned short, (_Float16)h);
    unsigned int other = (unsigned int)__shfl_xor((int)mine, 1);
    if ((u & 1) == 0) {
      unsigned int packed = mine | (other << 16);
      __hip_atomic_store(&hnxt[(b * 1024 + U) >> 1], packed, __ATOMIC_RELAXED,
                         __HIP_MEMORY_SCOPE_AGENT);
    }
    if (t == 511) {
      out[(size_t)33554432 + b * 1024 + U] = h;  // hy
      out[(size_t)33619968 + b * 1024 + U] = c;  // cy
      break;                                     // no final barrier needed
    }

    // ---- grid barrier: flag-array, no RMW, no cache maintenance ----
    __builtin_amdgcn_s_waitcnt(0x0F70);  // vmcnt(0): h stores acked at coherence point
    __syncthreads();                     // all waves drained
    if (tid == 0)
      __hip_atomic_store(&flags[p * 32], (unsigned)(t + 1), __ATOMIC_RELAXED,
                         __HIP_MEMORY_SCOPE_AGENT);
    const unsigned tgt = (unsigned)(t + 1);
    int done;
    do {
      unsigned v = __hip_atomic_load(&flags[tid * 32], __ATOMIC_RELAXED,
                                     __HIP_MEMORY_SCOPE_AGENT);
      done = __syncthreads_and((int)(v >= tgt));
      if (!done) __builtin_amdgcn_s_sleep(4);
    } while (!done);
    asm volatile("" ::: "memory");  // keep next step's h loads after the barrier
  }
}

// ---------------- launch ----------------
extern "C" void kernel_launch(void* const* d_in, const int* in_sizes, int n_in,
                              void* d_out, int out_size, void* d_ws, size_t ws_size,
                              hipStream_t stream) {
  const float* x    = (const float*)d_in[0];
  const float* hx   = (const float*)d_in[1];
  const float* cxp  = (const float*)d_in[2];
  const float* w_ii = (const float*)d_in[3];
  const float* w_fi = (const float*)d_in[4];
  const float* w_ai = (const float*)d_in[5];
  const float* w_oi = (const float*)d_in[6];
  const float* w_ih = (const float*)d_in[7];
  const float* w_fh = (const float*)d_in[8];
  const float* w_ah = (const float*)d_in[9];
  const float* w_oh = (const float*)d_in[10];
  const float* b_i  = (const float*)d_in[11];
  const float* b_f  = (const float*)d_in[12];
  const float* b_a  = (const float*)d_in[13];
  const float* b_o  = (const float*)d_in[14];
  float* out = (float*)d_out;

  char* ws = (char*)d_ws;
  _Float16* Xh       = (_Float16*)(ws);                 // 64 MB (dead after gemm_g)
  unsigned int* flags = (unsigned int*)(ws);            // 32 KB, aliases Xh (zeroed post-gemm)
  _Float16* Wip      = (_Float16*)(ws + 67108864);      // 8 MB
  _Float16* Whp      = (_Float16*)(ws + 75497472);      // 8 MB
  float* biasp       = (float*)(ws + 83886080);         // 16 KB
  unsigned int* hbuf = (unsigned int*)(ws + 83902464);  // 256 KB (2 packed buffers)
  _Float16* G        = (_Float16*)(ws + 84164864);      // 256 MB
  if (ws_size < (size_t)84164864 + 268435456) return;   // insufficient workspace

  cvt_x_kernel<<<32768, 256, 0, stream>>>(x, Xh, 33554432);
  build_w_kernel<<<8193, 256, 0, stream>>>(w_ii, w_fi, w_ai, w_oi, w_ih, w_fh, w_ah, w_oh,
                                           b_i, b_f, b_a, b_o, Wip, Whp, biasp);
  init_h_kernel<<<128, 256, 0, stream>>>(hx, hbuf);
  gemm_g_kernel<<<dim3(256, 32), 256, 0, stream>>>(Xh, Wip, biasp, G);
  zero_flags_kernel<<<32, 256, 0, stream>>>(flags);
  lstm_rec_kernel<<<256, 256, 0, stream>>>(G, Whp, hbuf, cxp, out, flags);
}

// Round 3
// 3805.437 us; speedup vs baseline: 7.1062x; 1.6217x over previous
//
#include <hip/hip_runtime.h>
#include <cstdint>

typedef _Float16 half8 __attribute__((ext_vector_type(8)));
typedef _Float16 half4v __attribute__((ext_vector_type(4)));
typedef float floatx4 __attribute__((ext_vector_type(4)));
typedef unsigned long long u64;

__device__ __forceinline__ float sig_(float x) { return 1.f / (1.f + __expf(-x)); }
__device__ __forceinline__ float tanh_(float x) {
  x = fminf(15.f, fmaxf(-15.f, x));
  float e = __expf(2.f * x);
  return (e - 1.f) / (e + 1.f);
}

// ---------------- prep kernels ----------------
__global__ void cvt_x_kernel(const float* __restrict__ x, _Float16* __restrict__ xh, int n) {
  int i = (blockIdx.x * 256 + threadIdx.x) * 4;
  if (i < n) {
    const float4 v = *(const float4*)(x + i);
    half4v o = {(_Float16)v.x, (_Float16)v.y, (_Float16)v.z, (_Float16)v.w};
    *(half4v*)(xh + i) = o;
  }
}

// Permuted weights: row n of W*perm = w_{g}[u][:], u=n>>2, g=n&3.
// Block p of the recurrent kernel owns contiguous perm-cols [16p,16p+16).
__global__ void build_w_kernel(const float* w0, const float* w1, const float* w2, const float* w3,
                               const float* w4, const float* w5, const float* w6, const float* w7,
                               const float* b0, const float* b1, const float* b2, const float* b3,
                               _Float16* __restrict__ Wip, _Float16* __restrict__ Whp,
                               float* __restrict__ biasp) {
  int n = blockIdx.x;
  if (n < 8192) {
    const float* srcs[8] = {w0, w1, w2, w3, w4, w5, w6, w7};
    int which = n >> 12;
    int row = n & 4095;
    int u = row >> 2, g = row & 3;
    const float* s = srcs[which * 4 + g] + (size_t)u * 1024;
    _Float16* dst = (which ? Whp : Wip) + (size_t)row * 1024;
    int t = threadIdx.x * 4;
    float4 v = *(const float4*)(s + t);
    half4v o = {(_Float16)v.x, (_Float16)v.y, (_Float16)v.z, (_Float16)v.w};
    *(half4v*)(dst + t) = o;
  } else {
    const float* bs[4] = {b0, b1, b2, b3};
    for (int idx = threadIdx.x; idx < 4096; idx += 256)
      biasp[idx] = bs[idx & 3][idx >> 2];
  }
}

// h buffers: fp16 pairs packed in u32, row-major [batch][unit]
__global__ void init_h_kernel(const float* __restrict__ hx, unsigned int* __restrict__ hbuf) {
  int i = blockIdx.x * 256 + threadIdx.x;
  if (i < 32768) {
    unsigned short lo = __builtin_bit_cast(unsigned short, (_Float16)hx[2 * i]);
    unsigned short hi = __builtin_bit_cast(unsigned short, (_Float16)hx[2 * i + 1]);
    hbuf[i] = (unsigned int)lo | ((unsigned int)hi << 16);
  }
}

__global__ void zero_flags_kernel(unsigned int* __restrict__ flags) {
  int i = blockIdx.x * 256 + threadIdx.x;
  if (i < 8192) flags[i] = 0u;
}

// ---------------- precompute GEMM ----------------
// G3 layout (fp16): [p(256)][t(512)][i(4)][kg(4)][ml(16)][r(4)] — matches rec-kernel
// lane layout so the rec kernel reads one coalesced u64 per thread per step.
__global__ __launch_bounds__(256) void gemm_g_kernel(const _Float16* __restrict__ Xh,
                                                     const _Float16* __restrict__ Wp,
                                                     const float* __restrict__ biasp,
                                                     _Float16* __restrict__ G3) {
  __shared__ _Float16 Al[4][128][8];
  __shared__ _Float16 Bl[4][128][8];
  const int tid = threadIdx.x;
  const int w = tid >> 6, l = tid & 63;
  const int wm = (w >> 1) * 64, wn = (w & 1) * 64;
  const int ml = l & 15, kg = l >> 4;
  const int bm = blockIdx.x, bn = blockIdx.y;
  const int r0 = tid & 127, kc0 = tid >> 7;
  const int kc1 = kc0 + 2;
  const size_t arow0 = (size_t)(bm * 128 + r0) * 1024;
  const size_t brow0 = (size_t)(bn * 128 + r0) * 1024;
  floatx4 acc[4][4] = {};
  for (int kt = 0; kt < 1024; kt += 32) {
    __syncthreads();
    __builtin_amdgcn_global_load_lds(
        (const __attribute__((address_space(1))) unsigned int*)(Xh + arow0 + kt + kc0 * 8),
        (__attribute__((address_space(3))) unsigned int*)&Al[kc0][r0][0], 16, 0, 0);
    __builtin_amdgcn_global_load_lds(
        (const __attribute__((address_space(1))) unsigned int*)(Xh + arow0 + kt + kc1 * 8),
        (__attribute__((address_space(3))) unsigned int*)&Al[kc1][r0][0], 16, 0, 0);
    __builtin_amdgcn_global_load_lds(
        (const __attribute__((address_space(1))) unsigned int*)(Wp + brow0 + kt + kc0 * 8),
        (__attribute__((address_space(3))) unsigned int*)&Bl[kc0][r0][0], 16, 0, 0);
    __builtin_amdgcn_global_load_lds(
        (const __attribute__((address_space(1))) unsigned int*)(Wp + brow0 + kt + kc1 * 8),
        (__attribute__((address_space(3))) unsigned int*)&Bl[kc1][r0][0], 16, 0, 0);
    __syncthreads();
    half8 af[4], bf[4];
#pragma unroll
    for (int i = 0; i < 4; ++i) af[i] = *(const half8*)&Al[kg][wm + i * 16 + ml][0];
#pragma unroll
    for (int j = 0; j < 4; ++j) bf[j] = *(const half8*)&Bl[kg][wn + j * 16 + ml][0];
#pragma unroll
    for (int i = 0; i < 4; ++i)
#pragma unroll
      for (int j = 0; j < 4; ++j)
        acc[i][j] = __builtin_amdgcn_mfma_f32_16x16x32_f16(af[i], bf[j], acc[i][j], 0, 0, 0);
  }
  const int t = (bm * 128 + wm) >> 6;  // wm in {0,64} -> t const per wave
#pragma unroll
  for (int j = 0; j < 4; ++j) {
    const int col = bn * 128 + wn + j * 16 + ml;
    const float bj = biasp[col];
    const int p = col >> 4;
#pragma unroll
    for (int i = 0; i < 4; ++i) {
      half4v pk = {(_Float16)(acc[i][j][0] + bj), (_Float16)(acc[i][j][1] + bj),
                   (_Float16)(acc[i][j][2] + bj), (_Float16)(acc[i][j][3] + bj)};
      *(half4v*)&G3[((size_t)p * 512 + t) * 1024 + i * 256 + kg * 64 + ml * 4] = pk;
    }
  }
}

// ---------------- persistent recurrent kernel ----------------
// 256 blocks (1/CU) x 4 waves. Block p owns units [4p,4p+4) = perm cols [16p,16p+16).
// Wh fragments persistent in registers (128 VGPR). Each wave stages its own 16 h-rows
// into its private LDS slice with coalesced agent-atomic u64 loads; XOR-swizzled so
// frag ds_read_b128 is conflict-free. No __syncthreads in the compute phase.
__global__ __launch_bounds__(256, 1) void lstm_rec_kernel(
    const _Float16* __restrict__ G3, const _Float16* __restrict__ Whp,
    unsigned int* __restrict__ hbuf, const float* __restrict__ cx,
    float* __restrict__ out, unsigned int* __restrict__ flags) {
  const int p = blockIdx.x, tid = threadIdx.x;
  const int w = tid >> 6, l = tid & 63;
  const int ml = l & 15, kg = l >> 4;
  __shared__ _Float16 hl_[32768];        // 64 KB; wave w slice = hl_[w*8192 ..]
  char* hl = (char*)(hl_ + w * 8192);    // 16 rows x 512 fp16 (1024 B/row)

  // persistent Wh B-fragments: lane (ml,kg) holds Whp[16p+ml][s*32+kg*8 .. +8]
  half8 wfr[32];
#pragma unroll
  for (int s = 0; s < 32; ++s)
    wfr[s] = *(const half8*)&Whp[(size_t)(16 * p + ml) * 1024 + s * 32 + kg * 8];

  const int bl = l >> 2, u = l & 3;
  const int bglob = 16 * w + bl, U = 4 * p + u;
  float c = cx[bglob * 1024 + U];
  __syncthreads();

  for (int t = 0; t < 512; ++t) {
    const u64* hq = (const u64*)(hbuf + (size_t)(t & 1) * 32768);
    u64* hnq = (u64*)(hbuf + (size_t)((t & 1) ^ 1) * 32768);

    // ---- issue all global traffic up front (coalesced) ----
    u64 c1[32], c2[32];
#pragma unroll
    for (int i = 0; i < 32; ++i) {
      const int row = i >> 1, j = ((i & 1) << 6) + l;
      c1[i] = __hip_atomic_load(&hq[(size_t)(16 * w + row) * 256 + j], __ATOMIC_RELAXED,
                                __HIP_MEMORY_SCOPE_AGENT);
    }
    const u64 ginb =
        *(const u64*)&G3[((size_t)p * 512 + t) * 1024 + w * 256 + kg * 64 + ml * 4];
#pragma unroll
    for (int i = 0; i < 32; ++i) {
      const int row = i >> 1, j = ((i & 1) << 6) + l;
      c2[i] = __hip_atomic_load(&hq[(size_t)(16 * w + row) * 256 + 128 + j], __ATOMIC_RELAXED,
                                __HIP_MEMORY_SCOPE_AGENT);
    }

    // ---- chunk 1: stage + MFMA (same-wave LDS, no block sync) ----
#pragma unroll
    for (int i = 0; i < 32; ++i) {
      const int row = i >> 1, j = ((i & 1) << 6) + l;
      const int un = (j >> 1) ^ (row & 7);
      *(u64*)(hl + row * 1024 + un * 16 + (j & 1) * 8) = c1[i];
    }
    __builtin_amdgcn_wave_barrier();
    floatx4 acc[4] = {};
#pragma unroll
    for (int s = 0; s < 16; ++s) {
      const int un = (s * 4 + kg) ^ (ml & 7);
      half8 a = *(const half8*)(hl + ml * 1024 + un * 16);
      acc[s & 3] = __builtin_amdgcn_mfma_f32_16x16x32_f16(a, wfr[s], acc[s & 3], 0, 0, 0);
    }
    __builtin_amdgcn_wave_barrier();
    // ---- chunk 2 ----
#pragma unroll
    for (int i = 0; i < 32; ++i) {
      const int row = i >> 1, j = ((i & 1) << 6) + l;
      const int un = (j >> 1) ^ (row & 7);
      *(u64*)(hl + row * 1024 + un * 16 + (j & 1) * 8) = c2[i];
    }
    __builtin_amdgcn_wave_barrier();
#pragma unroll
    for (int s = 0; s < 16; ++s) {
      const int un = (s * 4 + kg) ^ (ml & 7);
      half8 a = *(const half8*)(hl + ml * 1024 + un * 16);
      acc[s & 3] = __builtin_amdgcn_mfma_f32_16x16x32_f16(a, wfr[16 + s], acc[s & 3], 0, 0, 0);
    }
    floatx4 a4 = (acc[0] + acc[1]) + (acc[2] + acc[3]);

    // ---- intra-wave gate exchange in own slice (frag reads already issued) ----
    union { u64 q; half4v h4; } gu; gu.q = ginb;
    float* glw = (float*)hl;  // 16x20 f32 = 1280 B, inside own 16 KB slice
    __builtin_amdgcn_wave_barrier();
#pragma unroll
    for (int r = 0; r < 4; ++r)
      glw[(kg * 4 + r) * 20 + ml] = a4[r] + (float)gu.h4[r];
    __builtin_amdgcn_wave_barrier();
    const float4 g4 = *(const float4*)&glw[bl * 20 + u * 4];

    const float ig = sig_(g4.x), fg = sig_(g4.y);
    const float ag = tanh_(g4.z), og = sig_(g4.w);
    c = fg * c + ig * ag;
    const float h = og * tanh_(c);

    // publish: pack 4 units/batch -> one u64 agent store from lane u==0
    unsigned int mine = (unsigned int)__builtin_bit_cast(unsigned short, (_Float16)h);
    unsigned int pair = mine | (((unsigned int)__shfl_xor((int)mine, 1)) << 16);
    u64 quad = (u64)pair | ((u64)(unsigned int)__shfl_xor((int)pair, 2) << 32);
    if (u == 0)
      __hip_atomic_store(&hnq[(size_t)bglob * 256 + p], quad, __ATOMIC_RELAXED,
                         __HIP_MEMORY_SCOPE_AGENT);

    if (t == 511) {
      out[(size_t)t * 65536 + bglob * 1024 + U] = h;
      out[(size_t)33554432 + bglob * 1024 + U] = h;  // hy
      out[(size_t)33619968 + bglob * 1024 + U] = c;  // cy
      break;
    }

    // ---- grid barrier (flag array, no RMW) ----
    __builtin_amdgcn_s_waitcnt(0x0F70);  // vmcnt(0): publish acked at coherence point
    __syncthreads();
    if (tid == 0)
      __hip_atomic_store(&flags[p * 32], (unsigned)(t + 1), __ATOMIC_RELAXED,
                         __HIP_MEMORY_SCOPE_AGENT);
    out[(size_t)t * 65536 + bglob * 1024 + U] = h;  // off the critical path
    const unsigned tgt = (unsigned)(t + 1);
    int done;
    do {
      unsigned v = __hip_atomic_load(&flags[tid * 32], __ATOMIC_RELAXED,
                                     __HIP_MEMORY_SCOPE_AGENT);
      done = __syncthreads_and((int)(v >= tgt));
      if (!done) __builtin_amdgcn_s_sleep(2);
    } while (!done);
    asm volatile("" ::: "memory");
  }
}

// ---------------- launch ----------------
extern "C" void kernel_launch(void* const* d_in, const int* in_sizes, int n_in,
                              void* d_out, int out_size, void* d_ws, size_t ws_size,
                              hipStream_t stream) {
  const float* x    = (const float*)d_in[0];
  const float* hx   = (const float*)d_in[1];
  const float* cxp  = (const float*)d_in[2];
  const float* w_ii = (const float*)d_in[3];
  const float* w_fi = (const float*)d_in[4];
  const float* w_ai = (const float*)d_in[5];
  const float* w_oi = (const float*)d_in[6];
  const float* w_ih = (const float*)d_in[7];
  const float* w_fh = (const float*)d_in[8];
  const float* w_ah = (const float*)d_in[9];
  const float* w_oh = (const float*)d_in[10];
  const float* b_i  = (const float*)d_in[11];
  const float* b_f  = (const float*)d_in[12];
  const float* b_a  = (const float*)d_in[13];
  const float* b_o  = (const float*)d_in[14];
  float* out = (float*)d_out;

  char* ws = (char*)d_ws;
  _Float16* Xh        = (_Float16*)(ws);                 // 64 MB (dead after gemm_g)
  unsigned int* flags = (unsigned int*)(ws);             // 32 KB, aliases Xh
  _Float16* Wip       = (_Float16*)(ws + 67108864);      // 8 MB
  _Float16* Whp       = (_Float16*)(ws + 75497472);      // 8 MB
  float* biasp        = (float*)(ws + 83886080);         // 16 KB
  unsigned int* hbuf  = (unsigned int*)(ws + 83902464);  // 256 KB (2 packed buffers)
  _Float16* G3        = (_Float16*)(ws + 84164864);      // 256 MB
  if (ws_size < (size_t)84164864 + 268435456) return;

  cvt_x_kernel<<<32768, 256, 0, stream>>>(x, Xh, 33554432);
  build_w_kernel<<<8193, 256, 0, stream>>>(w_ii, w_fi, w_ai, w_oi, w_ih, w_fh, w_ah, w_oh,
                                           b_i, b_f, b_a, b_o, Wip, Whp, biasp);
  init_h_kernel<<<128, 256, 0, stream>>>(hx, hbuf);
  gemm_g_kernel<<<dim3(256, 32), 256, 0, stream>>>(Xh, Wip, biasp, G3);
  zero_flags_kernel<<<32, 256, 0, stream>>>(flags);
  lstm_rec_kernel<<<256, 256, 0, stream>>>(G3, Whp, hbuf, cxp, out, flags);
}